// Round 1
// baseline (9.256 us; speedup 1.0000x reference)
//
#include <hip/hip_runtime.h>

// Reference collapses to a constant:
//   final layer: heads=1, out_ch=1, concat=False  -> h shape [N, 1]
//   return softmax(h, axis=1)  -> softmax over a length-1 axis == 1.0 everywhere
// (The reference source itself notes "[N,1] -> all ones".)
// Therefore the exact output is out_size float32 ones; everything else is dead code.

__global__ void fill_ones_kernel(float4* __restrict__ out4, int n4,
                                 float* __restrict__ out_tail, int tail_start, int n) {
    int i = blockIdx.x * blockDim.x + threadIdx.x;
    const float4 ones = make_float4(1.0f, 1.0f, 1.0f, 1.0f);
    for (int idx = i; idx < n4; idx += gridDim.x * blockDim.x) {
        out4[idx] = ones;
    }
    // tail (n % 4 elements) — handled by the first few threads of block 0
    if (blockIdx.x == 0 && threadIdx.x < (n - tail_start)) {
        out_tail[tail_start + threadIdx.x] = 1.0f;
    }
}

extern "C" void kernel_launch(void* const* d_in, const int* in_sizes, int n_in,
                              void* d_out, int out_size, void* d_ws, size_t ws_size,
                              hipStream_t stream) {
    (void)d_in; (void)in_sizes; (void)n_in; (void)d_ws; (void)ws_size;

    float* out = (float*)d_out;
    int n  = out_size;          // 100000 (float32 elements)
    int n4 = n / 4;             // float4 stores
    int tail_start = n4 * 4;

    int block = 256;
    int grid = (n4 + block - 1) / block;
    if (grid < 1) grid = 1;
    if (grid > 2048) grid = 2048;   // grid-stride covers the rest

    fill_ones_kernel<<<grid, block, 0, stream>>>(
        (float4*)out, n4, out, tail_start, n);
}